// Round 14
// baseline (180.238 us; speedup 1.0000x reference)
//
#include <hip/hip_runtime.h>
#include <hip/hip_bf16.h>

// MSSA: x(8,2048,512) -> qkv = x@Wqkv ; scores = (q*s)@(k*s)^T over FULL 512 dims ;
// attn = softmax ; out = attn@v ; result = (out + x)@Wout + bout
//
// R14: sgemm256 -> 4-phase/K-tile schedule (m201-derived): per phase
//   {ds_read quadrant || issue stage asyncs} ; raw s_barrier (NO vmcnt drain) ;
//   lgkmcnt(0)+sched_barrier ; setprio(1) 16 MFMA setprio(0) ; raw s_barrier.
//   All 8 next-tile asyncs issued in phases 0-1 -> loads span ~5 barriers;
//   single vmcnt(0) at tile boundary only (issue/consume tile-aligned w/ dbuf).
//   R13 result: swizzle zeroed bank conflicts but MfmaUtil stuck at 21% ->
//   stall is the 2-phase drain schedule, not LDS (T3/T4 mechanism).
// pvgemm/qkv/out: frozen R13 bodies (isolated change).
//
// Workspace (128 MiB): qkvb 50.3 | VT 16.8 | S 67.1 (pre-sgemm: xb+WT alias in S)
// LESSONS: R3/R4 512-thr regs cap 256/wave. R9 exp off PV K-loop. R10 dbuf@BK32
// window too small. R12 BK64 linear LDS = 16-way conflict. R13 swizzle: conflicts
// to 0 but schedule-bound.

typedef __attribute__((ext_vector_type(8))) short bf16x8;
typedef __attribute__((ext_vector_type(4))) float f32x4;

__device__ __forceinline__ unsigned short f2bf(float f) {
  unsigned u = __builtin_bit_cast(unsigned, f);
  u += 0x7fffu + ((u >> 16) & 1u);   // RNE
  return (unsigned short)(u >> 16);
}
__device__ __forceinline__ float bf2f(unsigned short h) {
  unsigned u = ((unsigned)h) << 16;
  return __builtin_bit_cast(float, u);
}

// async global->LDS, 16B/lane; LDS dest = wave-uniform base + lane*16 (HW rule)
__device__ __forceinline__ void async16(const unsigned short* g, unsigned short* l) {
  __builtin_amdgcn_global_load_lds(
      (const __attribute__((address_space(1))) unsigned int*)g,
      (__attribute__((address_space(3))) unsigned int*)l, 16, 0, 0);
}

// raw barrier with compiler memory fence (no waitcnt auto-insertion)
__device__ __forceinline__ void bar() { asm volatile("s_barrier" ::: "memory"); }

// ---------------- prep_x: xb = bf16(X) ----------------
__global__ __launch_bounds__(256) void prep_x(const float* __restrict__ X,
                                              unsigned short* __restrict__ XB) {
  const size_t base = ((size_t)blockIdx.x * 256 + threadIdx.x) * 16;
  f32x4 a0 = *(const f32x4*)&X[base];
  f32x4 a1 = *(const f32x4*)&X[base + 4];
  f32x4 a2 = *(const f32x4*)&X[base + 8];
  f32x4 a3 = *(const f32x4*)&X[base + 12];
  bf16x8 o0, o1;
#pragma unroll
  for (int j = 0; j < 4; ++j) {
    o0[j] = (short)f2bf(a0[j]);
    o0[4 + j] = (short)f2bf(a1[j]);
    o1[j] = (short)f2bf(a2[j]);
    o1[4 + j] = (short)f2bf(a3[j]);
  }
  *(bf16x8*)&XB[base] = o0;
  *(bf16x8*)&XB[base + 8] = o1;
}

// ---------------- prep_w: WT[c][k] = bf16(Wqkv[k][c] * (c<1024 ? 0.125 : 1)) ----------------
__global__ __launch_bounds__(256) void prep_w(const float* __restrict__ W,
                                              unsigned short* __restrict__ WT) {
  const int t = threadIdx.x;
  const int c0 = blockIdx.x * 128 + (t & 15) * 8;
  const int k0 = blockIdx.y * 128 + (t >> 4) * 8;
  float r[8][8];
#pragma unroll
  for (int j = 0; j < 8; ++j) {
    f32x4 lo = *(const f32x4*)&W[(size_t)(k0 + j) * 1536 + c0];
    f32x4 hi = *(const f32x4*)&W[(size_t)(k0 + j) * 1536 + c0 + 4];
#pragma unroll
    for (int q = 0; q < 4; ++q) {
      r[j][q] = lo[q];
      r[j][4 + q] = hi[q];
    }
  }
#pragma unroll
  for (int i = 0; i < 8; ++i) {
    const float scl = (c0 + i < 1024) ? 0.125f : 1.0f;
    bf16x8 o;
#pragma unroll
    for (int j = 0; j < 8; ++j) o[j] = (short)f2bf(r[j][i] * scl);
    *(bf16x8*)&WT[(size_t)(c0 + i) * 512 + k0] = o;
  }
}

// ---------------- transpose_wout: WoutT[c][k] = bf16(Wout[k][c]) ----------------
__global__ __launch_bounds__(256) void transpose_wout(const float* __restrict__ W,
                                                      unsigned short* __restrict__ WT) {
  const int t = threadIdx.x;
  const int c0 = blockIdx.x * 128 + (t & 15) * 8;
  const int k0 = blockIdx.y * 128 + (t >> 4) * 8;
  float r[8][8];
#pragma unroll
  for (int j = 0; j < 8; ++j) {
    f32x4 lo = *(const f32x4*)&W[(size_t)(k0 + j) * 512 + c0];
    f32x4 hi = *(const f32x4*)&W[(size_t)(k0 + j) * 512 + c0 + 4];
#pragma unroll
    for (int q = 0; q < 4; ++q) {
      r[j][q] = lo[q];
      r[j][4 + q] = hi[q];
    }
  }
#pragma unroll
  for (int i = 0; i < 8; ++i) {
    bf16x8 o;
#pragma unroll
    for (int j = 0; j < 8; ++j) o[j] = (short)f2bf(r[j][i]);
    *(bf16x8*)&WT[(size_t)(c0 + i) * 512 + k0] = o;
  }
}

// ---------------- Transpose V: VT[d][m] = qkv[m][1024+d] ----------------
__global__ __launch_bounds__(256) void transpose_v(const unsigned short* __restrict__ QKV,
                                                   unsigned short* __restrict__ VT) {
  const int t = threadIdx.x;
  const int m0 = blockIdx.x * 128 + (t & 15) * 8;
  const int d0 = blockIdx.y * 128 + (t >> 4) * 8;
  bf16x8 r[8];
#pragma unroll
  for (int j = 0; j < 8; ++j)
    r[j] = *(const bf16x8*)&QKV[(size_t)(m0 + j) * 1536 + 1024 + d0];
#pragma unroll
  for (int i = 0; i < 8; ++i) {
    bf16x8 o;
#pragma unroll
    for (int j = 0; j < 8; ++j) o[j] = r[j][i];
    *(bf16x8*)&VT[(size_t)(d0 + i) * 16384 + m0] = o;
  }
}

// ======== R8 single-buf 128x128 GEMM body (BK=32) -- qkv/out only ========

#define GEMM97_VARS                                            \
  const int tid = threadIdx.x;                                 \
  const int wave = tid >> 6, lane = tid & 63;                  \
  const int wr = wave >> 1, wc = wave & 1;                     \
  const int lg = lane >> 4, ll = lane & 15;                    \
  const int kk = lg * 8;                                       \
  const int srow = wave * 32 + (lane >> 2);                    \
  const int scol = (lane & 3) * 8;

#define GEMM97_BODY(AG, ASTR, BG, BSTR, KDIM)                                            \
  __shared__ __align__(16) unsigned short Asm[4096];                                     \
  __shared__ __align__(16) unsigned short Bsm[4096];                                     \
  GEMM97_VARS                                                                            \
  f32x4 acc[4][4];                                                                       \
  _Pragma("unroll") for (int i = 0; i < 4; ++i) _Pragma("unroll") for (int j = 0; j < 4; \
                                                                       ++j) acc[i][j] =  \
      (f32x4){0.f, 0.f, 0.f, 0.f};                                                       \
  for (int kt = 0; kt < KDIM; kt += 32) {                                                \
    async16(&AG[(size_t)srow * ASTR + kt + scol], &Asm[wave * 1024]);                    \
    async16(&AG[(size_t)(srow + 16) * ASTR + kt + scol], &Asm[wave * 1024 + 512]);       \
    async16(&BG[(size_t)srow * BSTR + kt + scol], &Bsm[wave * 1024]);                    \
    async16(&BG[(size_t)(srow + 16) * BSTR + kt + scol], &Bsm[wave * 1024 + 512]);       \
    __syncthreads();                                                                     \
    bf16x8 af[4], bfr[4];                                                                \
    _Pragma("unroll") for (int ai = 0; ai < 4; ++ai) af[ai] =                            \
        *(const bf16x8*)&Asm[(wr * 64 + ai * 16 + ll) * 32 + kk];                        \
    _Pragma("unroll") for (int bj = 0; bj < 4; ++bj) bfr[bj] =                           \
        *(const bf16x8*)&Bsm[(wc * 64 + bj * 16 + ll) * 32 + kk];                        \
    _Pragma("unroll") for (int ai = 0; ai < 4; ++ai) _Pragma("unroll") for (int bj = 0;  \
                                                                            bj < 4;      \
                                                                            ++bj)        \
        acc[ai][bj] =                                                                    \
        __builtin_amdgcn_mfma_f32_16x16x32_bf16(af[ai], bfr[bj], acc[ai][bj], 0, 0, 0);  \
    __syncthreads();                                                                     \
  }

// qkv = xb @ WT^T (scale pre-folded into WT)
__global__ __launch_bounds__(256, 3) void gemm_qkv97(const unsigned short* __restrict__ XB,
                                                     const unsigned short* __restrict__ WT,
                                                     unsigned short* __restrict__ QKV) {
  const int bid = blockIdx.x;
  const int qt = bid / 12, nt = bid - qt * 12;
  const unsigned short* Ag = XB + (size_t)(qt * 128) * 512;
  const unsigned short* Bg = WT + (size_t)(nt * 128) * 512;
  GEMM97_BODY(Ag, 512, Bg, 512, 512)
#pragma unroll
  for (int ai = 0; ai < 4; ++ai)
#pragma unroll
    for (int bj = 0; bj < 4; ++bj) {
      const int col = nt * 128 + wc * 64 + bj * 16 + ll;
#pragma unroll
      for (int r = 0; r < 4; ++r) {
        const int row = qt * 128 + wr * 64 + ai * 16 + lg * 4 + r;
        QKV[(size_t)row * 1536 + col] = f2bf(acc[ai][bj][r]);
      }
    }
}

// ======== sgemm: 256x256, 8 waves, BK=64, dbuf, T2-swizzled, 4-PHASE schedule ========
__global__ __launch_bounds__(512) void sgemm256(const unsigned short* __restrict__ QKV,
                                                unsigned short* __restrict__ S,
                                                float* __restrict__ part) {
  __shared__ __align__(16) unsigned short Asm[2][16384];  // [buf][256*64]
  __shared__ __align__(16) unsigned short Bsm[2][16384];
  const int tid = threadIdx.x;
  const int wave = tid >> 6, lane = tid & 63;
  const int wr = wave >> 2, wc = wave & 3;
  const int lg = lane >> 4, ll = lane & 15;
  const int bid = blockIdx.x;
  const int b = bid & 7;  // batch -> XCD
  const int idx = bid >> 3;
  const int kvt = idx & 7, qt = idx >> 3;
  const unsigned short* Ag = QKV + ((size_t)b * 2048 + qt * 256) * 1536;
  const unsigned short* Bg = QKV + ((size_t)b * 2048 + kvt * 256) * 1536 + 512;
  const int sr = wave * 8 + (lane >> 3);                  // staging row (+64*i)
  const int sc = (((lane & 7) ^ ((lane >> 3) & 7))) * 8;  // PRE-SWIZZLED source col
  const int kb0 = ((lg) ^ (ll & 7)) * 8;                  // swizzled read col, k-half 0
  const int kb1 = ((4 + lg) ^ (ll & 7)) * 8;              // swizzled read col, k-half 1

  f32x4 acc[8][4];
#pragma unroll
  for (int i = 0; i < 8; ++i)
#pragma unroll
    for (int j = 0; j < 4; ++j) acc[i][j] = (f32x4){0.f, 0.f, 0.f, 0.f};

  int aoff[8], boff[4];
#pragma unroll
  for (int i = 0; i < 8; ++i) aoff[i] = (wr * 128 + i * 16 + ll) * 64;
#pragma unroll
  for (int j = 0; j < 4; ++j) boff[j] = (wc * 64 + j * 16 + ll) * 64;

#define SGA(BUF, KT, I) async16(&Ag[(size_t)((I)*64 + sr) * 1536 + (KT) + sc], \
                                &Asm[BUF][((I)*64 + wave * 8) * 64])
#define SGB(BUF, KT, I) async16(&Bg[(size_t)((I)*64 + sr) * 1536 + (KT) + sc], \
                                &Bsm[BUF][((I)*64 + wave * 8) * 64])

  // prologue: stage tile 0 into buf 0, full drain
#pragma unroll
  for (int i = 0; i < 4; ++i) { SGA(0, 0, i); SGB(0, 0, i); }
  asm volatile("s_waitcnt vmcnt(0)" ::: "memory");
  __syncthreads();

  int cur = 0;
  for (int t = 0; t < 8; ++t) {
    const int ktn = t * 64 + 64;
    const int nxt = cur ^ 1;
    bf16x8 af[4], af2[4], bfr[4];
    // ---- phase 0: kk0, ai 0-3 (+ stage A of tile t+1) ----
#pragma unroll
    for (int ai = 0; ai < 4; ++ai) af[ai] = *(const bf16x8*)&Asm[cur][aoff[ai] + kb0];
#pragma unroll
    for (int bj = 0; bj < 4; ++bj) bfr[bj] = *(const bf16x8*)&Bsm[cur][boff[bj] + kb0];
    if (t < 7) {
#pragma unroll
      for (int i = 0; i < 4; ++i) SGA(nxt, ktn, i);
    }
    bar();
    asm volatile("s_waitcnt lgkmcnt(0)" ::: "memory");
    __builtin_amdgcn_sched_barrier(0);
    __builtin_amdgcn_s_setprio(1);
#pragma unroll
    for (int ai = 0; ai < 4; ++ai)
#pragma unroll
      for (int bj = 0; bj < 4; ++bj)
        acc[ai][bj] = __builtin_amdgcn_mfma_f32_16x16x32_bf16(af[ai], bfr[bj], acc[ai][bj], 0, 0, 0);
    __builtin_amdgcn_s_setprio(0);
    bar();
    // ---- phase 1: kk0, ai 4-7 (+ stage B of tile t+1) ----
#pragma unroll
    for (int ai = 0; ai < 4; ++ai) af2[ai] = *(const bf16x8*)&Asm[cur][aoff[4 + ai] + kb0];
    if (t < 7) {
#pragma unroll
      for (int i = 0; i < 4; ++i) SGB(nxt, ktn, i);
    }
    bar();
    asm volatile("s_waitcnt lgkmcnt(0)" ::: "memory");
    __builtin_amdgcn_sched_barrier(0);
    __builtin_amdgcn_s_setprio(1);
#pragma unroll
    for (int ai = 0; ai < 4; ++ai)
#pragma unroll
      for (int bj = 0; bj < 4; ++bj)
        acc[4 + ai][bj] = __builtin_amdgcn_mfma_f32_16x16x32_bf16(af2[ai], bfr[bj], acc[4 + ai][bj], 0, 0, 0);
    __builtin_amdgcn_s_setprio(0);
    bar();
    // ---- phase 2: kk1, ai 0-3 ----
#pragma unroll
    for (int ai = 0; ai < 4; ++ai) af[ai] = *(const bf16x8*)&Asm[cur][aoff[ai] + kb1];
#pragma unroll
    for (int bj = 0; bj < 4; ++bj) bfr[bj] = *(const bf16x8*)&Bsm[cur][boff[bj] + kb1];
    bar();
    asm volatile("s_waitcnt lgkmcnt(0)" ::: "memory");
    __builtin_amdgcn_sched_barrier(0);
    __builtin_amdgcn_s_setprio(1);
#pragma unroll
    for (int ai = 0; ai < 4; ++ai)
#pragma unroll
      for (int bj = 0; bj < 4; ++bj)
        acc[ai][bj] = __builtin_amdgcn_mfma_f32_16x16x32_bf16(af[ai], bfr[bj], acc[ai][bj], 0, 0, 0);
    __builtin_amdgcn_s_setprio(0);
    bar();
    // ---- phase 3: kk1, ai 4-7 ; tile-boundary vmcnt drain ----
#pragma unroll
    for (int ai = 0; ai < 4; ++ai) af2[ai] = *(const bf16x8*)&Asm[cur][aoff[4 + ai] + kb1];
    bar();
    asm volatile("s_waitcnt lgkmcnt(0)" ::: "memory");
    __builtin_amdgcn_sched_barrier(0);
    __builtin_amdgcn_s_setprio(1);
#pragma unroll
    for (int ai = 0; ai < 4; ++ai)
#pragma unroll
      for (int bj = 0; bj < 4; ++bj)
        acc[4 + ai][bj] = __builtin_amdgcn_mfma_f32_16x16x32_bf16(af2[ai], bfr[bj], acc[4 + ai][bj], 0, 0, 0);
    __builtin_amdgcn_s_setprio(0);
    asm volatile("s_waitcnt vmcnt(0)" ::: "memory");  // tile t+1 staged (per-wave) ...
    bar();                                            // ... and published block-wide
    cur = nxt;
  }
#undef SGA
#undef SGB

  // exp (max-free) + per-(row, wc) partial sums over this wave's 64 cols
#pragma unroll
  for (int ai = 0; ai < 8; ++ai)
#pragma unroll
    for (int bj = 0; bj < 4; ++bj)
#pragma unroll
      for (int r = 0; r < 4; ++r) acc[ai][bj][r] = __expf(acc[ai][bj][r]);

#pragma unroll
  for (int ai = 0; ai < 8; ++ai)
#pragma unroll
    for (int r = 0; r < 4; ++r) {
      float se = (acc[ai][0][r] + acc[ai][1][r]) + (acc[ai][2][r] + acc[ai][3][r]);
      se += __shfl_xor(se, 1);
      se += __shfl_xor(se, 2);
      se += __shfl_xor(se, 4);
      se += __shfl_xor(se, 8);
      if (ll == 0) {
        const size_t rowg = (size_t)b * 2048 + qt * 256 + wr * 128 + ai * 16 + lg * 4 + r;
        part[rowg * 32 + kvt * 4 + wc] = se;
      }
    }

  unsigned short* Sg = S + (size_t)b * 2048 * 2048;
#pragma unroll
  for (int ai = 0; ai < 8; ++ai)
#pragma unroll
    for (int bj = 0; bj < 4; ++bj) {
      const int col = kvt * 256 + wc * 64 + bj * 16 + ll;
#pragma unroll
      for (int r = 0; r < 4; ++r) {
        const int row = qt * 256 + wr * 128 + ai * 16 + lg * 4 + r;
        Sg[(size_t)row * 2048 + col] = f2bf(acc[ai][bj][r]);
      }
    }
}

// fold 32 per-(tile,wavecol) sums -> per-row 1/l
__global__ __launch_bounds__(256) void combine_l(const float* __restrict__ part,
                                                 float* __restrict__ invl) {
  const int row = blockIdx.x * 256 + threadIdx.x;
  float l = 0.f;
#pragma unroll
  for (int t = 0; t < 8; ++t) {
    f32x4 v = *(const f32x4*)&part[(size_t)row * 32 + t * 4];
    l += (v[0] + v[1]) + (v[2] + v[3]);
  }
  invl[row] = 1.0f / l;
}

// res = (P~ @ V) * invl + x  -- 128x128, BK=64, dbuf, stage-early, T2-swizzled (R13)
__global__ __launch_bounds__(256, 3) void pvgemm97(const unsigned short* __restrict__ S,
                                                   const unsigned short* __restrict__ VT,
                                                   const float* __restrict__ X,
                                                   const float* __restrict__ invl,
                                                   unsigned short* __restrict__ RES) {
  __shared__ __align__(16) unsigned short Asm[2][8192];  // [buf][128*64]
  __shared__ __align__(16) unsigned short Bsm[2][8192];
  const int tid = threadIdx.x;
  const int wave = tid >> 6, lane = tid & 63;
  const int wr = wave >> 1, wc = wave & 1;
  const int lg = lane >> 4, ll = lane & 15;
  const int bid = blockIdx.x;
  const int b = bid & 7;
  const int idx = bid >> 3;
  const int dt = idx & 3, qt = idx >> 2;
  const unsigned short* Ag = S + (size_t)b * 2048 * 2048 + (size_t)(qt * 128) * 2048;
  const unsigned short* Bg = VT + (size_t)(dt * 128) * 16384 + (size_t)b * 2048;
  const int sr = wave * 32 + (lane >> 3);                 // +8*i
  const int sc = (((lane & 7) ^ ((lane >> 3) & 7))) * 8;  // PRE-SWIZZLED source col

  f32x4 acc[4][4];
#pragma unroll
  for (int i = 0; i < 4; ++i)
#pragma unroll
    for (int j = 0; j < 4; ++j) acc[i][j] = (f32x4){0.f, 0.f, 0.f, 0.f};

#define PV_STAGE(BUF, KT)                                                                   \
  _Pragma("unroll") for (int i = 0; i < 4; ++i) {                                           \
    async16(&Ag[(size_t)(sr + i * 8) * 2048 + (KT) + sc], &Asm[BUF][(wave * 32 + i * 8) * 64]);  \
    async16(&Bg[(size_t)(sr + i * 8) * 16384 + (KT) + sc], &Bsm[BUF][(wave * 32 + i * 8) * 64]); \
  }

  PV_STAGE(0, 0)
  int cur = 0;
  __syncthreads();
  for (int kt = 0; kt < 2048; kt += 64) {
    if (kt + 64 < 2048) {
      if (cur) { PV_STAGE(0, kt + 64) } else { PV_STAGE(1, kt + 64) }
    }
#pragma unroll
    for (int half = 0; half < 2; ++half) {
      const int kb = (((half * 4 + lg) ^ (ll & 7))) * 8;  // swizzled read col
      bf16x8 af[4], bf4[4];
#pragma unroll
      for (int ai = 0; ai < 4; ++ai)
        af[ai] = *(const bf16x8*)&Asm[cur][(wr * 64 + ai * 16 + ll) * 64 + kb];
#pragma unroll
      for (int bj = 0; bj < 4; ++bj)
        bf4[bj] = *(const bf16x8*)&Bsm[cur][(wc * 64 + bj * 16 + ll) * 64 + kb];
#pragma unroll
      for (int ai = 0; ai < 4; ++ai)
#pragma unroll
        for (int bj = 0; bj < 4; ++bj)
          acc[ai][bj] = __builtin_amdgcn_mfma_f32_16x16x32_bf16(af[ai], bf4[bj], acc[ai][bj], 0, 0, 0);
    }
    __syncthreads();
    cur ^= 1;
  }
#undef PV_STAGE

  const int rowbase = b * 2048 + qt * 128 + wr * 64;
  float il[4][4];
#pragma unroll
  for (int ai = 0; ai < 4; ++ai)
#pragma unroll
    for (int r = 0; r < 4; ++r) il[ai][r] = invl[rowbase + ai * 16 + lg * 4 + r];
#pragma unroll
  for (int ai = 0; ai < 4; ++ai)
#pragma unroll
    for (int bj = 0; bj < 4; ++bj) {
      const int col = dt * 128 + wc * 64 + bj * 16 + ll;
#pragma unroll
      for (int r = 0; r < 4; ++r) {
        const size_t row = (size_t)rowbase + ai * 16 + lg * 4 + r;
        const float val = acc[ai][bj][r] * il[ai][r] + X[row * 512 + col];
        RES[row * 1536 + 1024 + col] = f2bf(val);
      }
    }
}

// out = res @ WoutT^T + bout (fp32 out)
__global__ __launch_bounds__(256, 3) void gemm_out97(const unsigned short* __restrict__ A,
                                                     const unsigned short* __restrict__ WT,
                                                     const float* __restrict__ bias,
                                                     float* __restrict__ OUT) {
  const int bid = blockIdx.x;
  const int dt = bid & 3, qt = bid >> 2;
  const unsigned short* Ag = A + (size_t)(qt * 128) * 1536 + 1024;
  const unsigned short* Bg = WT + (size_t)(dt * 128) * 512;
  GEMM97_BODY(Ag, 1536, Bg, 512, 512)
#pragma unroll
  for (int ai = 0; ai < 4; ++ai)
#pragma unroll
    for (int bj = 0; bj < 4; ++bj) {
      const int col = dt * 128 + wc * 64 + bj * 16 + ll;
      const float bv = bias[col];
#pragma unroll
      for (int r = 0; r < 4; ++r) {
        const int row = qt * 128 + wr * 64 + ai * 16 + lg * 4 + r;
        OUT[(size_t)row * 512 + col] = acc[ai][bj][r] + bv;
      }
    }
}

extern "C" void kernel_launch(void* const* d_in, const int* in_sizes, int n_in,
                              void* d_out, int out_size, void* d_ws, size_t ws_size,
                              hipStream_t stream) {
  const float* x = (const float*)d_in[0];     // [8,2048,512]
  const float* Wqkv = (const float*)d_in[1];  // [512,1536]
  const float* Wout = (const float*)d_in[2];  // [512,512]
  const float* bout = (const float*)d_in[3];  // [512]
  float* out = (float*)d_out;                 // [8,2048,512] fp32

  unsigned short* qkvb = (unsigned short*)d_ws;        // 16384*1536 bf16 = 50.3MB
  unsigned short* VT = qkvb + (size_t)16384 * 1536;    // 512*16384  bf16 = 16.8MB
  unsigned short* S = VT + (size_t)512 * 16384;        // 8*2048*2048 bf16 = 67.1MB
  unsigned short* xb = S;                              // bf16 X (dead before sgemm)
  unsigned short* WT = S + (size_t)16384 * 512;        // Wqkv^T scaled (dead before sgemm)
  unsigned short* WoutT = VT;                          // VT dead after pvgemm
  // softmax scratch inside d_out (fully overwritten by gemm_out97 at the end):
  float* part = out;                                   // [16384][32] f32 = 2MB
  float* invl = out + (size_t)16384 * 32;              // [16384] f32 = 64KB

  prep_x<<<2048, 256, 0, stream>>>(x, xb);
  prep_w<<<dim3(12, 4), 256, 0, stream>>>(Wqkv, WT);
  gemm_qkv97<<<1536, 256, 0, stream>>>(xb, WT, qkvb);
  transpose_v<<<dim3(128, 4), 256, 0, stream>>>(qkvb, VT);
  sgemm256<<<512, 512, 0, stream>>>(qkvb, S, part);
  combine_l<<<64, 256, 0, stream>>>(part, invl);
  pvgemm97<<<512, 256, 0, stream>>>(S, VT, x, invl, qkvb);
  transpose_wout<<<dim3(4, 4), 256, 0, stream>>>(Wout, WoutT);
  gemm_out97<<<512, 256, 0, stream>>>(qkvb, WoutT, bout, out);
}

// Round 15
// 179.737 us; speedup vs baseline: 1.0028x; 1.0028x over previous
//
#include <hip/hip_runtime.h>
#include <hip/hip_bf16.h>

// MSSA: x(8,2048,512) -> qkv = x@Wqkv ; scores = (q*s)@(k*s)^T over FULL 512 dims ;
// attn = softmax ; out = attn@v ; result = (out + x)@Wout + bout
//
// R15: pass-fusion round (R14 lesson: phase-schedule ports are neutral here; the
// 2-phase stage-early body is the local optimum -> remove whole passes instead).
//  - prep_x DELETED: gemm_qkv reg-stages A from fp32 X (convert + ds_write, free
//    2-way bank pattern), with next-tile A prefetched into regs (T14). B via
//    global_load_lds from pre-transposed WT.
//  - transpose_v DELETED: qkv v-blocks (nt>=8, uniform branch) write acc directly
//    to VT[d][m] (r-dim rows contiguous -> packed ushort4, 32B segments).
//  - sgemm256: R13 exact (2-phase stage-early dbuf, T2 swizzle, conflicts=0).
//  - pvgemm97: R13 exact. gemm_out97: R8 body.
//  - Max-free fused softmax (scores O(1)): sgemm epilogue exp + partial sums;
//    combine_l -> invl; pv epilogue acc*invl + x. Scratch in d_out.
//
// Workspace (128 MiB): qkvb 50.3 | VT 16.8 | S 67.1 (pre-sgemm: WT aliases S)
// LESSONS: R3/R4 512-thr regs cap 256/wave. R9 exp off PV K-loop. R12 BK64 linear
// LDS = 16-way conflict; R13 swizzle fixed it (conflicts->0). R14 4-phase: neutral.

typedef __attribute__((ext_vector_type(8))) short bf16x8;
typedef __attribute__((ext_vector_type(4))) float f32x4;
typedef __attribute__((ext_vector_type(4))) unsigned short u16x4;

__device__ __forceinline__ unsigned short f2bf(float f) {
  unsigned u = __builtin_bit_cast(unsigned, f);
  u += 0x7fffu + ((u >> 16) & 1u);   // RNE
  return (unsigned short)(u >> 16);
}
__device__ __forceinline__ float bf2f(unsigned short h) {
  unsigned u = ((unsigned)h) << 16;
  return __builtin_bit_cast(float, u);
}

// async global->LDS, 16B/lane; LDS dest = wave-uniform base + lane*16 (HW rule)
__device__ __forceinline__ void async16(const unsigned short* g, unsigned short* l) {
  __builtin_amdgcn_global_load_lds(
      (const __attribute__((address_space(1))) unsigned int*)g,
      (__attribute__((address_space(3))) unsigned int*)l, 16, 0, 0);
}

// ---------------- prep_w: WT[c][k] = bf16(Wqkv[k][c] * (c<1024 ? 0.125 : 1)) ----------------
__global__ __launch_bounds__(256) void prep_w(const float* __restrict__ W,
                                              unsigned short* __restrict__ WT) {
  const int t = threadIdx.x;
  const int c0 = blockIdx.x * 128 + (t & 15) * 8;
  const int k0 = blockIdx.y * 128 + (t >> 4) * 8;
  float r[8][8];
#pragma unroll
  for (int j = 0; j < 8; ++j) {
    f32x4 lo = *(const f32x4*)&W[(size_t)(k0 + j) * 1536 + c0];
    f32x4 hi = *(const f32x4*)&W[(size_t)(k0 + j) * 1536 + c0 + 4];
#pragma unroll
    for (int q = 0; q < 4; ++q) {
      r[j][q] = lo[q];
      r[j][4 + q] = hi[q];
    }
  }
#pragma unroll
  for (int i = 0; i < 8; ++i) {
    const float scl = (c0 + i < 1024) ? 0.125f : 1.0f;
    bf16x8 o;
#pragma unroll
    for (int j = 0; j < 8; ++j) o[j] = (short)f2bf(r[j][i] * scl);
    *(bf16x8*)&WT[(size_t)(c0 + i) * 512 + k0] = o;
  }
}

// ---------------- transpose_wout: WoutT[c][k] = bf16(Wout[k][c]) ----------------
__global__ __launch_bounds__(256) void transpose_wout(const float* __restrict__ W,
                                                      unsigned short* __restrict__ WT) {
  const int t = threadIdx.x;
  const int c0 = blockIdx.x * 128 + (t & 15) * 8;
  const int k0 = blockIdx.y * 128 + (t >> 4) * 8;
  float r[8][8];
#pragma unroll
  for (int j = 0; j < 8; ++j) {
    f32x4 lo = *(const f32x4*)&W[(size_t)(k0 + j) * 512 + c0];
    f32x4 hi = *(const f32x4*)&W[(size_t)(k0 + j) * 512 + c0 + 4];
#pragma unroll
    for (int q = 0; q < 4; ++q) {
      r[j][q] = lo[q];
      r[j][4 + q] = hi[q];
    }
  }
#pragma unroll
  for (int i = 0; i < 8; ++i) {
    bf16x8 o;
#pragma unroll
    for (int j = 0; j < 8; ++j) o[j] = (short)f2bf(r[j][i]);
    *(bf16x8*)&WT[(size_t)(c0 + i) * 512 + k0] = o;
  }
}

#define GEMM97_VARS                                            \
  const int tid = threadIdx.x;                                 \
  const int wave = tid >> 6, lane = tid & 63;                  \
  const int wr = wave >> 1, wc = wave & 1;                     \
  const int lg = lane >> 4, ll = lane & 15;                    \
  const int kk = lg * 8;                                       \
  const int srow = wave * 32 + (lane >> 2);                    \
  const int scol = (lane & 3) * 8;

// ======== fused GEMM1: qkv = bf16(X) @ WT^T ; q/k -> qkvb, v -> VT directly ========
// A: fp32 reg-staged (convert + ds_write, next tile prefetched into regs).
// B: global_load_lds. 2 barriers/K-step (R8 structure).
__global__ __launch_bounds__(256, 3) void gemm_qkv_fused(const float* __restrict__ X,
                                                         const unsigned short* __restrict__ WT,
                                                         unsigned short* __restrict__ QKV,
                                                         unsigned short* __restrict__ VT) {
  __shared__ __align__(16) unsigned short Asm[4096];
  __shared__ __align__(16) unsigned short Bsm[4096];
  GEMM97_VARS
  const int bid = blockIdx.x;
  const int qt = bid / 12, nt = bid - qt * 12;
  const float* Ag = X + (size_t)(qt * 128) * 512;
  const unsigned short* Bg = WT + (size_t)(nt * 128) * 512;

  f32x4 acc[4][4];
#pragma unroll
  for (int i = 0; i < 4; ++i)
#pragma unroll
    for (int j = 0; j < 4; ++j) acc[i][j] = (f32x4){0.f, 0.f, 0.f, 0.f};

  // prologue: A(0) into regs
  f32x4 ar0 = *(const f32x4*)&Ag[(size_t)srow * 512 + scol];
  f32x4 ar1 = *(const f32x4*)&Ag[(size_t)srow * 512 + scol + 4];
  f32x4 ar2 = *(const f32x4*)&Ag[(size_t)(srow + 16) * 512 + scol];
  f32x4 ar3 = *(const f32x4*)&Ag[(size_t)(srow + 16) * 512 + scol + 4];

  for (int kt = 0; kt < 512; kt += 32) {
    async16(&Bg[(size_t)srow * 512 + kt + scol], &Bsm[wave * 1024]);
    async16(&Bg[(size_t)(srow + 16) * 512 + kt + scol], &Bsm[wave * 1024 + 512]);
    bf16x8 a0, a1;
#pragma unroll
    for (int j = 0; j < 4; ++j) {
      a0[j] = (short)f2bf(ar0[j]);
      a0[4 + j] = (short)f2bf(ar1[j]);
      a1[j] = (short)f2bf(ar2[j]);
      a1[4 + j] = (short)f2bf(ar3[j]);
    }
    *(bf16x8*)&Asm[srow * 32 + scol] = a0;
    *(bf16x8*)&Asm[(srow + 16) * 32 + scol] = a1;
    __syncthreads();  // drains B asyncs + A ds_writes
    if (kt + 32 < 512) {  // prefetch next A tile into regs (flies over MFMA)
      ar0 = *(const f32x4*)&Ag[(size_t)srow * 512 + kt + 32 + scol];
      ar1 = *(const f32x4*)&Ag[(size_t)srow * 512 + kt + 32 + scol + 4];
      ar2 = *(const f32x4*)&Ag[(size_t)(srow + 16) * 512 + kt + 32 + scol];
      ar3 = *(const f32x4*)&Ag[(size_t)(srow + 16) * 512 + kt + 32 + scol + 4];
    }
    bf16x8 af[4], bfr[4];
#pragma unroll
    for (int ai = 0; ai < 4; ++ai) af[ai] = *(const bf16x8*)&Asm[(wr * 64 + ai * 16 + ll) * 32 + kk];
#pragma unroll
    for (int bj = 0; bj < 4; ++bj) bfr[bj] = *(const bf16x8*)&Bsm[(wc * 64 + bj * 16 + ll) * 32 + kk];
#pragma unroll
    for (int ai = 0; ai < 4; ++ai)
#pragma unroll
      for (int bj = 0; bj < 4; ++bj)
        acc[ai][bj] = __builtin_amdgcn_mfma_f32_16x16x32_bf16(af[ai], bfr[bj], acc[ai][bj], 0, 0, 0);
    __syncthreads();
  }

  if (nt < 8) {  // q/k columns -> qkvb (block-uniform branch)
#pragma unroll
    for (int ai = 0; ai < 4; ++ai)
#pragma unroll
      for (int bj = 0; bj < 4; ++bj) {
        const int col = nt * 128 + wc * 64 + bj * 16 + ll;
#pragma unroll
        for (int r = 0; r < 4; ++r) {
          const int row = qt * 128 + wr * 64 + ai * 16 + lg * 4 + r;
          QKV[(size_t)row * 1536 + col] = f2bf(acc[ai][bj][r]);
        }
      }
  } else {  // v columns -> VT[d][m] directly (rows contiguous over r -> packed store)
#pragma unroll
    for (int ai = 0; ai < 4; ++ai)
#pragma unroll
      for (int bj = 0; bj < 4; ++bj) {
        const int d = (nt - 8) * 128 + wc * 64 + bj * 16 + ll;
        const int row0 = qt * 128 + wr * 64 + ai * 16 + lg * 4;
        u16x4 o;
#pragma unroll
        for (int r = 0; r < 4; ++r) o[r] = f2bf(acc[ai][bj][r]);
        *(u16x4*)&VT[(size_t)d * 16384 + row0] = o;
      }
  }
}

// ======== sgemm: 256x256, 8 waves, BK=64, dbuf, stage-early, T2-swizzled (R13) ========
__global__ __launch_bounds__(512) void sgemm256(const unsigned short* __restrict__ QKV,
                                                unsigned short* __restrict__ S,
                                                float* __restrict__ part) {
  __shared__ __align__(16) unsigned short Asm[2][16384];  // [buf][256*64]
  __shared__ __align__(16) unsigned short Bsm[2][16384];
  const int tid = threadIdx.x;
  const int wave = tid >> 6, lane = tid & 63;
  const int wr = wave >> 2, wc = wave & 3;
  const int lg = lane >> 4, ll = lane & 15;
  const int bid = blockIdx.x;
  const int b = bid & 7;  // batch -> XCD
  const int idx = bid >> 3;
  const int kvt = idx & 7, qt = idx >> 3;
  const unsigned short* Ag = QKV + ((size_t)b * 2048 + qt * 256) * 1536;
  const unsigned short* Bg = QKV + ((size_t)b * 2048 + kvt * 256) * 1536 + 512;
  const int sr = wave * 8 + (lane >> 3);                  // staging row (+64*i)
  const int sc = (((lane & 7) ^ ((lane >> 3) & 7))) * 8;  // PRE-SWIZZLED source col

  f32x4 acc[8][4];
#pragma unroll
  for (int i = 0; i < 8; ++i)
#pragma unroll
    for (int j = 0; j < 4; ++j) acc[i][j] = (f32x4){0.f, 0.f, 0.f, 0.f};

#define SG_STAGE(BUF, KT)                                                              \
  _Pragma("unroll") for (int i = 0; i < 4; ++i) {                                      \
    async16(&Ag[(size_t)(i * 64 + sr) * 1536 + (KT) + sc], &Asm[BUF][(i * 64 + wave * 8) * 64]); \
    async16(&Bg[(size_t)(i * 64 + sr) * 1536 + (KT) + sc], &Bsm[BUF][(i * 64 + wave * 8) * 64]); \
  }

  SG_STAGE(0, 0)
  int cur = 0;
  __syncthreads();
  for (int kt = 0; kt < 512; kt += 64) {
    if (kt + 64 < 512) {
      if (cur) { SG_STAGE(0, kt + 64) } else { SG_STAGE(1, kt + 64) }
    }
#pragma unroll
    for (int half = 0; half < 2; ++half) {
      const int kb = (((half * 4 + lg) ^ (ll & 7))) * 8;  // swizzled read col
      bf16x8 af[8], bf4[4];
#pragma unroll
      for (int ai = 0; ai < 8; ++ai)
        af[ai] = *(const bf16x8*)&Asm[cur][(wr * 128 + ai * 16 + ll) * 64 + kb];
#pragma unroll
      for (int bj = 0; bj < 4; ++bj)
        bf4[bj] = *(const bf16x8*)&Bsm[cur][(wc * 64 + bj * 16 + ll) * 64 + kb];
#pragma unroll
      for (int ai = 0; ai < 8; ++ai)
#pragma unroll
        for (int bj = 0; bj < 4; ++bj)
          acc[ai][bj] = __builtin_amdgcn_mfma_f32_16x16x32_bf16(af[ai], bf4[bj], acc[ai][bj], 0, 0, 0);
    }
    __syncthreads();  // drains next-tile asyncs + fences reads
    cur ^= 1;
  }
#undef SG_STAGE

  // exp (max-free) + per-(row, wc) partial sums over this wave's 64 cols
#pragma unroll
  for (int ai = 0; ai < 8; ++ai)
#pragma unroll
    for (int bj = 0; bj < 4; ++bj)
#pragma unroll
      for (int r = 0; r < 4; ++r) acc[ai][bj][r] = __expf(acc[ai][bj][r]);

#pragma unroll
  for (int ai = 0; ai < 8; ++ai)
#pragma unroll
    for (int r = 0; r < 4; ++r) {
      float se = (acc[ai][0][r] + acc[ai][1][r]) + (acc[ai][2][r] + acc[ai][3][r]);
      se += __shfl_xor(se, 1);
      se += __shfl_xor(se, 2);
      se += __shfl_xor(se, 4);
      se += __shfl_xor(se, 8);
      if (ll == 0) {
        const size_t rowg = (size_t)b * 2048 + qt * 256 + wr * 128 + ai * 16 + lg * 4 + r;
        part[rowg * 32 + kvt * 4 + wc] = se;
      }
    }

  unsigned short* Sg = S + (size_t)b * 2048 * 2048;
#pragma unroll
  for (int ai = 0; ai < 8; ++ai)
#pragma unroll
    for (int bj = 0; bj < 4; ++bj) {
      const int col = kvt * 256 + wc * 64 + bj * 16 + ll;
#pragma unroll
      for (int r = 0; r < 4; ++r) {
        const int row = qt * 256 + wr * 128 + ai * 16 + lg * 4 + r;
        Sg[(size_t)row * 2048 + col] = f2bf(acc[ai][bj][r]);
      }
    }
}

// fold 32 per-(tile,wavecol) sums -> per-row 1/l
__global__ __launch_bounds__(256) void combine_l(const float* __restrict__ part,
                                                 float* __restrict__ invl) {
  const int row = blockIdx.x * 256 + threadIdx.x;
  float l = 0.f;
#pragma unroll
  for (int t = 0; t < 8; ++t) {
    f32x4 v = *(const f32x4*)&part[(size_t)row * 32 + t * 4];
    l += (v[0] + v[1]) + (v[2] + v[3]);
  }
  invl[row] = 1.0f / l;
}

// res = (P~ @ V) * invl + x  -- 128x128, BK=64, dbuf, stage-early, T2-swizzled (R13)
__global__ __launch_bounds__(256, 3) void pvgemm97(const unsigned short* __restrict__ S,
                                                   const unsigned short* __restrict__ VT,
                                                   const float* __restrict__ X,
                                                   const float* __restrict__ invl,
                                                   unsigned short* __restrict__ RES) {
  __shared__ __align__(16) unsigned short Asm[2][8192];  // [buf][128*64]
  __shared__ __align__(16) unsigned short Bsm[2][8192];
  const int tid = threadIdx.x;
  const int wave = tid >> 6, lane = tid & 63;
  const int wr = wave >> 1, wc = wave & 1;
  const int lg = lane >> 4, ll = lane & 15;
  const int bid = blockIdx.x;
  const int b = bid & 7;
  const int idx = bid >> 3;
  const int dt = idx & 3, qt = idx >> 2;
  const unsigned short* Ag = S + (size_t)b * 2048 * 2048 + (size_t)(qt * 128) * 2048;
  const unsigned short* Bg = VT + (size_t)(dt * 128) * 16384 + (size_t)b * 2048;
  const int sr = wave * 32 + (lane >> 3);                 // +8*i
  const int sc = (((lane & 7) ^ ((lane >> 3) & 7))) * 8;  // PRE-SWIZZLED source col

  f32x4 acc[4][4];
#pragma unroll
  for (int i = 0; i < 4; ++i)
#pragma unroll
    for (int j = 0; j < 4; ++j) acc[i][j] = (f32x4){0.f, 0.f, 0.f, 0.f};

#define PV_STAGE(BUF, KT)                                                                   \
  _Pragma("unroll") for (int i = 0; i < 4; ++i) {                                           \
    async16(&Ag[(size_t)(sr + i * 8) * 2048 + (KT) + sc], &Asm[BUF][(wave * 32 + i * 8) * 64]);  \
    async16(&Bg[(size_t)(sr + i * 8) * 16384 + (KT) + sc], &Bsm[BUF][(wave * 32 + i * 8) * 64]); \
  }

  PV_STAGE(0, 0)
  int cur = 0;
  __syncthreads();
  for (int kt = 0; kt < 2048; kt += 64) {
    if (kt + 64 < 2048) {
      if (cur) { PV_STAGE(0, kt + 64) } else { PV_STAGE(1, kt + 64) }
    }
#pragma unroll
    for (int half = 0; half < 2; ++half) {
      const int kb = (((half * 4 + lg) ^ (ll & 7))) * 8;  // swizzled read col
      bf16x8 af[4], bf4[4];
#pragma unroll
      for (int ai = 0; ai < 4; ++ai)
        af[ai] = *(const bf16x8*)&Asm[cur][(wr * 64 + ai * 16 + ll) * 64 + kb];
#pragma unroll
      for (int bj = 0; bj < 4; ++bj)
        bf4[bj] = *(const bf16x8*)&Bsm[cur][(wc * 64 + bj * 16 + ll) * 64 + kb];
#pragma unroll
      for (int ai = 0; ai < 4; ++ai)
#pragma unroll
        for (int bj = 0; bj < 4; ++bj)
          acc[ai][bj] = __builtin_amdgcn_mfma_f32_16x16x32_bf16(af[ai], bf4[bj], acc[ai][bj], 0, 0, 0);
    }
    __syncthreads();
    cur ^= 1;
  }
#undef PV_STAGE

  const int rowbase = b * 2048 + qt * 128 + wr * 64;
  float il[4][4];
#pragma unroll
  for (int ai = 0; ai < 4; ++ai)
#pragma unroll
    for (int r = 0; r < 4; ++r) il[ai][r] = invl[rowbase + ai * 16 + lg * 4 + r];
#pragma unroll
  for (int ai = 0; ai < 4; ++ai)
#pragma unroll
    for (int bj = 0; bj < 4; ++bj) {
      const int col = dt * 128 + wc * 64 + bj * 16 + ll;
#pragma unroll
      for (int r = 0; r < 4; ++r) {
        const size_t row = (size_t)rowbase + ai * 16 + lg * 4 + r;
        const float val = acc[ai][bj][r] * il[ai][r] + X[row * 512 + col];
        RES[row * 1536 + 1024 + col] = f2bf(val);
      }
    }
}

// out = res @ WoutT^T + bout (fp32 out) -- R8 single-buf body
__global__ __launch_bounds__(256, 3) void gemm_out97(const unsigned short* __restrict__ A,
                                                     const unsigned short* __restrict__ WT,
                                                     const float* __restrict__ bias,
                                                     float* __restrict__ OUT) {
  __shared__ __align__(16) unsigned short Asm[4096];
  __shared__ __align__(16) unsigned short Bsm[4096];
  GEMM97_VARS
  const int bid = blockIdx.x;
  const int dt = bid & 3, qt = bid >> 2;
  const unsigned short* Ag = A + (size_t)(qt * 128) * 1536 + 1024;
  const unsigned short* Bg = WT + (size_t)(dt * 128) * 512;
  f32x4 acc[4][4];
#pragma unroll
  for (int i = 0; i < 4; ++i)
#pragma unroll
    for (int j = 0; j < 4; ++j) acc[i][j] = (f32x4){0.f, 0.f, 0.f, 0.f};
  for (int kt = 0; kt < 512; kt += 32) {
    async16(&Ag[(size_t)srow * 1536 + kt + scol], &Asm[wave * 1024]);
    async16(&Ag[(size_t)(srow + 16) * 1536 + kt + scol], &Asm[wave * 1024 + 512]);
    async16(&Bg[(size_t)srow * 512 + kt + scol], &Bsm[wave * 1024]);
    async16(&Bg[(size_t)(srow + 16) * 512 + kt + scol], &Bsm[wave * 1024 + 512]);
    __syncthreads();
    bf16x8 af[4], bfr[4];
#pragma unroll
    for (int ai = 0; ai < 4; ++ai) af[ai] = *(const bf16x8*)&Asm[(wr * 64 + ai * 16 + ll) * 32 + kk];
#pragma unroll
    for (int bj = 0; bj < 4; ++bj) bfr[bj] = *(const bf16x8*)&Bsm[(wc * 64 + bj * 16 + ll) * 32 + kk];
#pragma unroll
    for (int ai = 0; ai < 4; ++ai)
#pragma unroll
      for (int bj = 0; bj < 4; ++bj)
        acc[ai][bj] = __builtin_amdgcn_mfma_f32_16x16x32_bf16(af[ai], bfr[bj], acc[ai][bj], 0, 0, 0);
    __syncthreads();
  }
#pragma unroll
  for (int ai = 0; ai < 4; ++ai)
#pragma unroll
    for (int bj = 0; bj < 4; ++bj) {
      const int col = dt * 128 + wc * 64 + bj * 16 + ll;
      const float bv = bias[col];
#pragma unroll
      for (int r = 0; r < 4; ++r) {
        const int row = qt * 128 + wr * 64 + ai * 16 + lg * 4 + r;
        OUT[(size_t)row * 512 + col] = acc[ai][bj][r] + bv;
      }
    }
}

extern "C" void kernel_launch(void* const* d_in, const int* in_sizes, int n_in,
                              void* d_out, int out_size, void* d_ws, size_t ws_size,
                              hipStream_t stream) {
  const float* x = (const float*)d_in[0];     // [8,2048,512]
  const float* Wqkv = (const float*)d_in[1];  // [512,1536]
  const float* Wout = (const float*)d_in[2];  // [512,512]
  const float* bout = (const float*)d_in[3];  // [512]
  float* out = (float*)d_out;                 // [8,2048,512] fp32

  unsigned short* qkvb = (unsigned short*)d_ws;        // 16384*1536 bf16 = 50.3MB (q/k used)
  unsigned short* VT = qkvb + (size_t)16384 * 1536;    // 512*16384  bf16 = 16.8MB
  unsigned short* S = VT + (size_t)512 * 16384;        // 8*2048*2048 bf16 = 67.1MB
  unsigned short* WT = S;                              // Wqkv^T scaled (dead before sgemm)
  unsigned short* WoutT = S + (size_t)1536 * 512;      // Wout^T (S region, dead before sgemm? NO -- see below)
  // WoutT must survive until gemm_out: place it in qkvb's unused v-column space?
  // Simplest safe spot: end of S region is overwritten by sgemm... use the tail of
  // the workspace: S occupies bytes [67.1MB..134.2MB); WT (1.5MB) aliases S start.
  // WoutT (0.5MB) goes AFTER the S region if ws allows, else reuse VT? VT is live
  // until pvgemm. Use qkvb v-cols? They are overwritten by pvgemm RES... which
  // happens BEFORE gemm_out reads A from them -- but WoutT would clash with RES rows.
  // Robust choice: recompute WoutT every launch into WT's slot AFTER sgemm consumed
  // it: transpose_wout launches after pvgemm (original R13 order) into S start --
  // S is dead after pvgemm. That is exactly what we do below.
  float* part = out;                                   // [16384][32] f32 = 2MB
  float* invl = out + (size_t)16384 * 32;              // [16384] f32 = 64KB

  prep_w<<<dim3(12, 4), 256, 0, stream>>>(Wqkv, WT);
  gemm_qkv_fused<<<1536, 256, 0, stream>>>(x, WT, qkvb, VT);
  sgemm256<<<512, 512, 0, stream>>>(qkvb, S, part);
  combine_l<<<64, 256, 0, stream>>>(part, invl);
  pvgemm97<<<512, 256, 0, stream>>>(S, VT, x, invl, qkvb);
  transpose_wout<<<dim3(4, 4), 256, 0, stream>>>(Wout, (unsigned short*)S);  // S dead now
  gemm_out97<<<512, 256, 0, stream>>>(qkvb, (unsigned short*)S, bout, out);
}

// Round 16
// 173.278 us; speedup vs baseline: 1.0402x; 1.0373x over previous
//
#include <hip/hip_runtime.h>
#include <hip/hip_bf16.h>

// MSSA: x(8,2048,512) -> qkv = x@Wqkv ; scores = (q*s)@(k*s)^T over FULL 512 dims ;
// attn = softmax ; out = attn@v ; result = (out + x)@Wout + bout
//
// R16 = R13 + proven R15 delta only:
//  - prep_x RESTORED (R15 lesson: reading fp32 X directly in the GEMM re-reads
//    2x-bytes 12x -> 64.6us vs 51us split; bf16 xb + global_load_lds wins).
//  - gemm_qkv97 epilogue split KEPT: q/k -> qkvb, v -> VT[d][m] directly
//    (packed u16x4; transpose_v pass deleted; validated in R15).
//  - sgemm256: 2-phase stage-early dbuf, T2 swizzle (conflicts=0, R13).
//  - pvgemm97: 128x128 BK=64 dbuf stage-early swizzled (R13).
//  - Max-free fused softmax: sgemm epilogue exp + partial sums -> combine_l ->
//    invl; pv epilogue acc*invl + x. Scratch in d_out (overwritten by gemm_out).
//
// Workspace (128 MiB): qkvb 50.3 | VT 16.8 | S 67.1 (pre-sgemm: xb+WT alias S;
// post-pvgemm: WoutT aliases dead S).
// LESSONS: R3/R4 512-thr regs cap 256/wave. R9 exp off PV K-loop. R10/R11/R14
// schedule ports neutral; 2-phase stage-early is this structure's optimum.
// R12 BK64 linear LDS = 16-way conflict; R13 swizzle -> 0. R15 fp32-A fusion bad.

typedef __attribute__((ext_vector_type(8))) short bf16x8;
typedef __attribute__((ext_vector_type(4))) float f32x4;
typedef __attribute__((ext_vector_type(4))) unsigned short u16x4;

__device__ __forceinline__ unsigned short f2bf(float f) {
  unsigned u = __builtin_bit_cast(unsigned, f);
  u += 0x7fffu + ((u >> 16) & 1u);   // RNE
  return (unsigned short)(u >> 16);
}
__device__ __forceinline__ float bf2f(unsigned short h) {
  unsigned u = ((unsigned)h) << 16;
  return __builtin_bit_cast(float, u);
}

// async global->LDS, 16B/lane; LDS dest = wave-uniform base + lane*16 (HW rule)
__device__ __forceinline__ void async16(const unsigned short* g, unsigned short* l) {
  __builtin_amdgcn_global_load_lds(
      (const __attribute__((address_space(1))) unsigned int*)g,
      (__attribute__((address_space(3))) unsigned int*)l, 16, 0, 0);
}

// ---------------- prep_x: xb = bf16(X) ----------------
__global__ __launch_bounds__(256) void prep_x(const float* __restrict__ X,
                                              unsigned short* __restrict__ XB) {
  const size_t base = ((size_t)blockIdx.x * 256 + threadIdx.x) * 16;
  f32x4 a0 = *(const f32x4*)&X[base];
  f32x4 a1 = *(const f32x4*)&X[base + 4];
  f32x4 a2 = *(const f32x4*)&X[base + 8];
  f32x4 a3 = *(const f32x4*)&X[base + 12];
  bf16x8 o0, o1;
#pragma unroll
  for (int j = 0; j < 4; ++j) {
    o0[j] = (short)f2bf(a0[j]);
    o0[4 + j] = (short)f2bf(a1[j]);
    o1[j] = (short)f2bf(a2[j]);
    o1[4 + j] = (short)f2bf(a3[j]);
  }
  *(bf16x8*)&XB[base] = o0;
  *(bf16x8*)&XB[base + 8] = o1;
}

// ---------------- prep_w: WT[c][k] = bf16(Wqkv[k][c] * (c<1024 ? 0.125 : 1)) ----------------
__global__ __launch_bounds__(256) void prep_w(const float* __restrict__ W,
                                              unsigned short* __restrict__ WT) {
  const int t = threadIdx.x;
  const int c0 = blockIdx.x * 128 + (t & 15) * 8;
  const int k0 = blockIdx.y * 128 + (t >> 4) * 8;
  float r[8][8];
#pragma unroll
  for (int j = 0; j < 8; ++j) {
    f32x4 lo = *(const f32x4*)&W[(size_t)(k0 + j) * 1536 + c0];
    f32x4 hi = *(const f32x4*)&W[(size_t)(k0 + j) * 1536 + c0 + 4];
#pragma unroll
    for (int q = 0; q < 4; ++q) {
      r[j][q] = lo[q];
      r[j][4 + q] = hi[q];
    }
  }
#pragma unroll
  for (int i = 0; i < 8; ++i) {
    const float scl = (c0 + i < 1024) ? 0.125f : 1.0f;
    bf16x8 o;
#pragma unroll
    for (int j = 0; j < 8; ++j) o[j] = (short)f2bf(r[j][i] * scl);
    *(bf16x8*)&WT[(size_t)(c0 + i) * 512 + k0] = o;
  }
}

// ---------------- transpose_wout: WoutT[c][k] = bf16(Wout[k][c]) ----------------
__global__ __launch_bounds__(256) void transpose_wout(const float* __restrict__ W,
                                                      unsigned short* __restrict__ WT) {
  const int t = threadIdx.x;
  const int c0 = blockIdx.x * 128 + (t & 15) * 8;
  const int k0 = blockIdx.y * 128 + (t >> 4) * 8;
  float r[8][8];
#pragma unroll
  for (int j = 0; j < 8; ++j) {
    f32x4 lo = *(const f32x4*)&W[(size_t)(k0 + j) * 512 + c0];
    f32x4 hi = *(const f32x4*)&W[(size_t)(k0 + j) * 512 + c0 + 4];
#pragma unroll
    for (int q = 0; q < 4; ++q) {
      r[j][q] = lo[q];
      r[j][4 + q] = hi[q];
    }
  }
#pragma unroll
  for (int i = 0; i < 8; ++i) {
    bf16x8 o;
#pragma unroll
    for (int j = 0; j < 8; ++j) o[j] = (short)f2bf(r[j][i]);
    *(bf16x8*)&WT[(size_t)(c0 + i) * 512 + k0] = o;
  }
}

#define GEMM97_VARS                                            \
  const int tid = threadIdx.x;                                 \
  const int wave = tid >> 6, lane = tid & 63;                  \
  const int wr = wave >> 1, wc = wave & 1;                     \
  const int lg = lane >> 4, ll = lane & 15;                    \
  const int kk = lg * 8;                                       \
  const int srow = wave * 32 + (lane >> 2);                    \
  const int scol = (lane & 3) * 8;

// ======== GEMM1: qkv = xb @ WT^T (R8/R13 body); q/k -> qkvb, v -> VT directly ========
__global__ __launch_bounds__(256, 3) void gemm_qkv97(const unsigned short* __restrict__ XB,
                                                     const unsigned short* __restrict__ WT,
                                                     unsigned short* __restrict__ QKV,
                                                     unsigned short* __restrict__ VT) {
  __shared__ __align__(16) unsigned short Asm[4096];
  __shared__ __align__(16) unsigned short Bsm[4096];
  GEMM97_VARS
  const int bid = blockIdx.x;
  const int qt = bid / 12, nt = bid - qt * 12;
  const unsigned short* Ag = XB + (size_t)(qt * 128) * 512;
  const unsigned short* Bg = WT + (size_t)(nt * 128) * 512;
  f32x4 acc[4][4];
#pragma unroll
  for (int i = 0; i < 4; ++i)
#pragma unroll
    for (int j = 0; j < 4; ++j) acc[i][j] = (f32x4){0.f, 0.f, 0.f, 0.f};
  for (int kt = 0; kt < 512; kt += 32) {
    async16(&Ag[(size_t)srow * 512 + kt + scol], &Asm[wave * 1024]);
    async16(&Ag[(size_t)(srow + 16) * 512 + kt + scol], &Asm[wave * 1024 + 512]);
    async16(&Bg[(size_t)srow * 512 + kt + scol], &Bsm[wave * 1024]);
    async16(&Bg[(size_t)(srow + 16) * 512 + kt + scol], &Bsm[wave * 1024 + 512]);
    __syncthreads();
    bf16x8 af[4], bfr[4];
#pragma unroll
    for (int ai = 0; ai < 4; ++ai) af[ai] = *(const bf16x8*)&Asm[(wr * 64 + ai * 16 + ll) * 32 + kk];
#pragma unroll
    for (int bj = 0; bj < 4; ++bj) bfr[bj] = *(const bf16x8*)&Bsm[(wc * 64 + bj * 16 + ll) * 32 + kk];
#pragma unroll
    for (int ai = 0; ai < 4; ++ai)
#pragma unroll
      for (int bj = 0; bj < 4; ++bj)
        acc[ai][bj] = __builtin_amdgcn_mfma_f32_16x16x32_bf16(af[ai], bfr[bj], acc[ai][bj], 0, 0, 0);
    __syncthreads();
  }
  if (nt < 8) {  // q/k columns -> qkvb (block-uniform branch)
#pragma unroll
    for (int ai = 0; ai < 4; ++ai)
#pragma unroll
      for (int bj = 0; bj < 4; ++bj) {
        const int col = nt * 128 + wc * 64 + bj * 16 + ll;
#pragma unroll
        for (int r = 0; r < 4; ++r) {
          const int row = qt * 128 + wr * 64 + ai * 16 + lg * 4 + r;
          QKV[(size_t)row * 1536 + col] = f2bf(acc[ai][bj][r]);
        }
      }
  } else {  // v columns -> VT[d][m] directly (r-rows contiguous -> packed u16x4)
#pragma unroll
    for (int ai = 0; ai < 4; ++ai)
#pragma unroll
      for (int bj = 0; bj < 4; ++bj) {
        const int d = (nt - 8) * 128 + wc * 64 + bj * 16 + ll;
        const int row0 = qt * 128 + wr * 64 + ai * 16 + lg * 4;
        u16x4 o;
#pragma unroll
        for (int r = 0; r < 4; ++r) o[r] = f2bf(acc[ai][bj][r]);
        *(u16x4*)&VT[(size_t)d * 16384 + row0] = o;
      }
  }
}

// ======== sgemm: 256x256, 8 waves, BK=64, dbuf, stage-early, T2-swizzled (R13) ========
__global__ __launch_bounds__(512) void sgemm256(const unsigned short* __restrict__ QKV,
                                                unsigned short* __restrict__ S,
                                                float* __restrict__ part) {
  __shared__ __align__(16) unsigned short Asm[2][16384];  // [buf][256*64]
  __shared__ __align__(16) unsigned short Bsm[2][16384];
  const int tid = threadIdx.x;
  const int wave = tid >> 6, lane = tid & 63;
  const int wr = wave >> 2, wc = wave & 3;
  const int lg = lane >> 4, ll = lane & 15;
  const int bid = blockIdx.x;
  const int b = bid & 7;  // batch -> XCD
  const int idx = bid >> 3;
  const int kvt = idx & 7, qt = idx >> 3;
  const unsigned short* Ag = QKV + ((size_t)b * 2048 + qt * 256) * 1536;
  const unsigned short* Bg = QKV + ((size_t)b * 2048 + kvt * 256) * 1536 + 512;
  const int sr = wave * 8 + (lane >> 3);                  // staging row (+64*i)
  const int sc = (((lane & 7) ^ ((lane >> 3) & 7))) * 8;  // PRE-SWIZZLED source col

  f32x4 acc[8][4];
#pragma unroll
  for (int i = 0; i < 8; ++i)
#pragma unroll
    for (int j = 0; j < 4; ++j) acc[i][j] = (f32x4){0.f, 0.f, 0.f, 0.f};

#define SG_STAGE(BUF, KT)                                                              \
  _Pragma("unroll") for (int i = 0; i < 4; ++i) {                                      \
    async16(&Ag[(size_t)(i * 64 + sr) * 1536 + (KT) + sc], &Asm[BUF][(i * 64 + wave * 8) * 64]); \
    async16(&Bg[(size_t)(i * 64 + sr) * 1536 + (KT) + sc], &Bsm[BUF][(i * 64 + wave * 8) * 64]); \
  }

  SG_STAGE(0, 0)
  int cur = 0;
  __syncthreads();
  for (int kt = 0; kt < 512; kt += 64) {
    if (kt + 64 < 512) {
      if (cur) { SG_STAGE(0, kt + 64) } else { SG_STAGE(1, kt + 64) }
    }
#pragma unroll
    for (int half = 0; half < 2; ++half) {
      const int kb = (((half * 4 + lg) ^ (ll & 7))) * 8;  // swizzled read col
      bf16x8 af[8], bf4[4];
#pragma unroll
      for (int ai = 0; ai < 8; ++ai)
        af[ai] = *(const bf16x8*)&Asm[cur][(wr * 128 + ai * 16 + ll) * 64 + kb];
#pragma unroll
      for (int bj = 0; bj < 4; ++bj)
        bf4[bj] = *(const bf16x8*)&Bsm[cur][(wc * 64 + bj * 16 + ll) * 64 + kb];
#pragma unroll
      for (int ai = 0; ai < 8; ++ai)
#pragma unroll
        for (int bj = 0; bj < 4; ++bj)
          acc[ai][bj] = __builtin_amdgcn_mfma_f32_16x16x32_bf16(af[ai], bf4[bj], acc[ai][bj], 0, 0, 0);
    }
    __syncthreads();  // drains next-tile asyncs + fences reads
    cur ^= 1;
  }
#undef SG_STAGE

  // exp (max-free) + per-(row, wc) partial sums over this wave's 64 cols
#pragma unroll
  for (int ai = 0; ai < 8; ++ai)
#pragma unroll
    for (int bj = 0; bj < 4; ++bj)
#pragma unroll
      for (int r = 0; r < 4; ++r) acc[ai][bj][r] = __expf(acc[ai][bj][r]);

#pragma unroll
  for (int ai = 0; ai < 8; ++ai)
#pragma unroll
    for (int r = 0; r < 4; ++r) {
      float se = (acc[ai][0][r] + acc[ai][1][r]) + (acc[ai][2][r] + acc[ai][3][r]);
      se += __shfl_xor(se, 1);
      se += __shfl_xor(se, 2);
      se += __shfl_xor(se, 4);
      se += __shfl_xor(se, 8);
      if (ll == 0) {
        const size_t rowg = (size_t)b * 2048 + qt * 256 + wr * 128 + ai * 16 + lg * 4 + r;
        part[rowg * 32 + kvt * 4 + wc] = se;
      }
    }

  unsigned short* Sg = S + (size_t)b * 2048 * 2048;
#pragma unroll
  for (int ai = 0; ai < 8; ++ai)
#pragma unroll
    for (int bj = 0; bj < 4; ++bj) {
      const int col = kvt * 256 + wc * 64 + bj * 16 + ll;
#pragma unroll
      for (int r = 0; r < 4; ++r) {
        const int row = qt * 256 + wr * 128 + ai * 16 + lg * 4 + r;
        Sg[(size_t)row * 2048 + col] = f2bf(acc[ai][bj][r]);
      }
    }
}

// fold 32 per-(tile,wavecol) sums -> per-row 1/l
__global__ __launch_bounds__(256) void combine_l(const float* __restrict__ part,
                                                 float* __restrict__ invl) {
  const int row = blockIdx.x * 256 + threadIdx.x;
  float l = 0.f;
#pragma unroll
  for (int t = 0; t < 8; ++t) {
    f32x4 v = *(const f32x4*)&part[(size_t)row * 32 + t * 4];
    l += (v[0] + v[1]) + (v[2] + v[3]);
  }
  invl[row] = 1.0f / l;
}

// res = (P~ @ V) * invl + x  -- 128x128, BK=64, dbuf, stage-early, T2-swizzled (R13)
__global__ __launch_bounds__(256, 3) void pvgemm97(const unsigned short* __restrict__ S,
                                                   const unsigned short* __restrict__ VT,
                                                   const float* __restrict__ X,
                                                   const float* __restrict__ invl,
                                                   unsigned short* __restrict__ RES) {
  __shared__ __align__(16) unsigned short Asm[2][8192];  // [buf][128*64]
  __shared__ __align__(16) unsigned short Bsm[2][8192];
  const int tid = threadIdx.x;
  const int wave = tid >> 6, lane = tid & 63;
  const int wr = wave >> 1, wc = wave & 1;
  const int lg = lane >> 4, ll = lane & 15;
  const int bid = blockIdx.x;
  const int b = bid & 7;
  const int idx = bid >> 3;
  const int dt = idx & 3, qt = idx >> 2;
  const unsigned short* Ag = S + (size_t)b * 2048 * 2048 + (size_t)(qt * 128) * 2048;
  const unsigned short* Bg = VT + (size_t)(dt * 128) * 16384 + (size_t)b * 2048;
  const int sr = wave * 32 + (lane >> 3);                 // +8*i
  const int sc = (((lane & 7) ^ ((lane >> 3) & 7))) * 8;  // PRE-SWIZZLED source col

  f32x4 acc[4][4];
#pragma unroll
  for (int i = 0; i < 4; ++i)
#pragma unroll
    for (int j = 0; j < 4; ++j) acc[i][j] = (f32x4){0.f, 0.f, 0.f, 0.f};

#define PV_STAGE(BUF, KT)                                                                   \
  _Pragma("unroll") for (int i = 0; i < 4; ++i) {                                           \
    async16(&Ag[(size_t)(sr + i * 8) * 2048 + (KT) + sc], &Asm[BUF][(wave * 32 + i * 8) * 64]);  \
    async16(&Bg[(size_t)(sr + i * 8) * 16384 + (KT) + sc], &Bsm[BUF][(wave * 32 + i * 8) * 64]); \
  }

  PV_STAGE(0, 0)
  int cur = 0;
  __syncthreads();
  for (int kt = 0; kt < 2048; kt += 64) {
    if (kt + 64 < 2048) {
      if (cur) { PV_STAGE(0, kt + 64) } else { PV_STAGE(1, kt + 64) }
    }
#pragma unroll
    for (int half = 0; half < 2; ++half) {
      const int kb = (((half * 4 + lg) ^ (ll & 7))) * 8;  // swizzled read col
      bf16x8 af[4], bf4[4];
#pragma unroll
      for (int ai = 0; ai < 4; ++ai)
        af[ai] = *(const bf16x8*)&Asm[cur][(wr * 64 + ai * 16 + ll) * 64 + kb];
#pragma unroll
      for (int bj = 0; bj < 4; ++bj)
        bf4[bj] = *(const bf16x8*)&Bsm[cur][(wc * 64 + bj * 16 + ll) * 64 + kb];
#pragma unroll
      for (int ai = 0; ai < 4; ++ai)
#pragma unroll
        for (int bj = 0; bj < 4; ++bj)
          acc[ai][bj] = __builtin_amdgcn_mfma_f32_16x16x32_bf16(af[ai], bf4[bj], acc[ai][bj], 0, 0, 0);
    }
    __syncthreads();
    cur ^= 1;
  }
#undef PV_STAGE

  const int rowbase = b * 2048 + qt * 128 + wr * 64;
  float il[4][4];
#pragma unroll
  for (int ai = 0; ai < 4; ++ai)
#pragma unroll
    for (int r = 0; r < 4; ++r) il[ai][r] = invl[rowbase + ai * 16 + lg * 4 + r];
#pragma unroll
  for (int ai = 0; ai < 4; ++ai)
#pragma unroll
    for (int bj = 0; bj < 4; ++bj) {
      const int col = dt * 128 + wc * 64 + bj * 16 + ll;
#pragma unroll
      for (int r = 0; r < 4; ++r) {
        const size_t row = (size_t)rowbase + ai * 16 + lg * 4 + r;
        const float val = acc[ai][bj][r] * il[ai][r] + X[row * 512 + col];
        RES[row * 1536 + 1024 + col] = f2bf(val);
      }
    }
}

// out = res @ WoutT^T + bout (fp32 out) -- R8 single-buf body
__global__ __launch_bounds__(256, 3) void gemm_out97(const unsigned short* __restrict__ A,
                                                     const unsigned short* __restrict__ WT,
                                                     const float* __restrict__ bias,
                                                     float* __restrict__ OUT) {
  __shared__ __align__(16) unsigned short Asm[4096];
  __shared__ __align__(16) unsigned short Bsm[4096];
  GEMM97_VARS
  const int bid = blockIdx.x;
  const int dt = bid & 3, qt = bid >> 2;
  const unsigned short* Ag = A + (size_t)(qt * 128) * 1536 + 1024;
  const unsigned short* Bg = WT + (size_t)(dt * 128) * 512;
  f32x4 acc[4][4];
#pragma unroll
  for (int i = 0; i < 4; ++i)
#pragma unroll
    for (int j = 0; j < 4; ++j) acc[i][j] = (f32x4){0.f, 0.f, 0.f, 0.f};
  for (int kt = 0; kt < 512; kt += 32) {
    async16(&Ag[(size_t)srow * 1536 + kt + scol], &Asm[wave * 1024]);
    async16(&Ag[(size_t)(srow + 16) * 1536 + kt + scol], &Asm[wave * 1024 + 512]);
    async16(&Bg[(size_t)srow * 512 + kt + scol], &Bsm[wave * 1024]);
    async16(&Bg[(size_t)(srow + 16) * 512 + kt + scol], &Bsm[wave * 1024 + 512]);
    __syncthreads();
    bf16x8 af[4], bfr[4];
#pragma unroll
    for (int ai = 0; ai < 4; ++ai) af[ai] = *(const bf16x8*)&Asm[(wr * 64 + ai * 16 + ll) * 32 + kk];
#pragma unroll
    for (int bj = 0; bj < 4; ++bj) bfr[bj] = *(const bf16x8*)&Bsm[(wc * 64 + bj * 16 + ll) * 32 + kk];
#pragma unroll
    for (int ai = 0; ai < 4; ++ai)
#pragma unroll
      for (int bj = 0; bj < 4; ++bj)
        acc[ai][bj] = __builtin_amdgcn_mfma_f32_16x16x32_bf16(af[ai], bfr[bj], acc[ai][bj], 0, 0, 0);
    __syncthreads();
  }
#pragma unroll
  for (int ai = 0; ai < 4; ++ai)
#pragma unroll
    for (int bj = 0; bj < 4; ++bj) {
      const int col = dt * 128 + wc * 64 + bj * 16 + ll;
      const float bv = bias[col];
#pragma unroll
      for (int r = 0; r < 4; ++r) {
        const int row = qt * 128 + wr * 64 + ai * 16 + lg * 4 + r;
        OUT[(size_t)row * 512 + col] = acc[ai][bj][r] + bv;
      }
    }
}

extern "C" void kernel_launch(void* const* d_in, const int* in_sizes, int n_in,
                              void* d_out, int out_size, void* d_ws, size_t ws_size,
                              hipStream_t stream) {
  const float* x = (const float*)d_in[0];     // [8,2048,512]
  const float* Wqkv = (const float*)d_in[1];  // [512,1536]
  const float* Wout = (const float*)d_in[2];  // [512,512]
  const float* bout = (const float*)d_in[3];  // [512]
  float* out = (float*)d_out;                 // [8,2048,512] fp32

  unsigned short* qkvb = (unsigned short*)d_ws;        // 16384*1536 bf16 (q/k cols used)
  unsigned short* VT = qkvb + (size_t)16384 * 1536;    // 512*16384 bf16 = 16.8MB
  unsigned short* S = VT + (size_t)512 * 16384;        // 8*2048*2048 bf16 = 67.1MB
  unsigned short* xb = S;                              // bf16 X (dead before sgemm)
  unsigned short* WT = S + (size_t)16384 * 512;        // Wqkv^T scaled (dead before sgemm)
  // WoutT: written into dead S start after pvgemm (R15-validated ordering)
  float* part = out;                                   // [16384][32] f32 = 2MB
  float* invl = out + (size_t)16384 * 32;              // [16384] f32 = 64KB

  prep_x<<<2048, 256, 0, stream>>>(x, xb);
  prep_w<<<dim3(12, 4), 256, 0, stream>>>(Wqkv, WT);
  gemm_qkv97<<<1536, 256, 0, stream>>>(xb, WT, qkvb, VT);
  sgemm256<<<512, 512, 0, stream>>>(qkvb, S, part);
  combine_l<<<64, 256, 0, stream>>>(part, invl);
  pvgemm97<<<512, 256, 0, stream>>>(S, VT, x, invl, qkvb);
  transpose_wout<<<dim3(4, 4), 256, 0, stream>>>(Wout, (unsigned short*)S);  // S dead now
  gemm_out97<<<512, 256, 0, stream>>>(qkvb, (unsigned short*)S, bout, out);
}